// Round 1
// baseline (286.718 us; speedup 1.0000x reference)
//
#include <hip/hip_runtime.h>

#define ZDIM 64
#define YDIM 128
#define XDIM 128
#define ZYX (ZDIM * YDIM * XDIM) /* 1048576 */
#define CAP 2048
#define MMAX 1024
#define KEPT_MAX 512
#define CLS_THR 0.5f
#define IOU_THR 0.5f

// ---------------- decode helper (matches reference _decode exactly) ----------
__device__ __forceinline__ void decode_one(const float* __restrict__ pb, int f,
                                           float& cx, float& cy, float& cz,
                                           float& w, float& h, float& l, float& th) {
    const float TM[8] = {-0.25f, 0.01f, 0.26f, 0.46f, 0.26f, 0.62f, 0.69f, 1.46f};
    const float TS[8] = {0.93f, 0.26f, 0.53f, 0.89f, 1.11f, 0.13f, 0.16f, 0.19f};
    int z = f >> 14;          // f / (Y*X)
    int y = (f >> 7) & 127;   // (f / X) % Y
    int x = f & 127;          // f % X
    float r[8];
#pragma unroll
    for (int c = 0; c < 8; ++c)
        r[c] = pb[(size_t)(c + 1) * ZYX + f] * TS[c] + TM[c];
    th = atan2f(r[1], r[0]);              // atan2(sin_t, cos_t)
    cx = (-16.0f + 0.25f * (float)x) + r[2];
    cy = (-16.0f + 0.25f * (float)y) + r[3];
    cz = (-16.0f + 0.5f * (float)z) + r[4];
    w = expf(r[5]);
    h = expf(r[6]);
    l = expf(r[7]);
}

// compute projected AABBs from 8 explicit corners (mirrors reference)
__device__ __forceinline__ void corner_boxes(float cx, float cy, float cz,
                                             float w, float h, float l, float th,
                                             float& xmn, float& ymn, float& xmx, float& ymx,
                                             float& zmn, float& zmx) {
    float ct = cosf(th), st = sinf(th);
    xmn = 1e30f; xmx = -1e30f; ymn = 1e30f; ymx = -1e30f; zmn = 1e30f; zmx = -1e30f;
#pragma unroll
    for (int k = 0; k < 8; ++k) {
        float sx = (k & 4) ? -1.0f : 1.0f;
        float sy = (k & 2) ? -1.0f : 1.0f;
        float sz = (k & 1) ? -1.0f : 1.0f;
        float ox = 0.5f * sx * w;
        float oy = 0.5f * sy * h;
        float oz = 0.5f * sz * l;
        float px = cx + ct * ox + st * oz;
        float py = cy + oy;
        float pz = cz - st * ox + ct * oz;
        xmn = fminf(xmn, px); xmx = fmaxf(xmx, px);
        ymn = fminf(ymn, py); ymx = fmaxf(ymx, py);
        zmn = fminf(zmn, pz); zmx = fmaxf(zmx, pz);
    }
}

// ---------------- kernel 1: compact candidates with score > CLS_THR ----------
__global__ __launch_bounds__(256) void collect_kernel(const float* __restrict__ points, int B,
                                                      int* __restrict__ cnt,
                                                      float* __restrict__ csc,
                                                      int* __restrict__ cidx) {
    int g = blockIdx.x * blockDim.x + threadIdx.x; // float4 index
    int per_b4 = ZYX / 4;
    int total4 = B * per_b4;
    if (g >= total4) return;
    int b = g / per_b4;
    int f4 = g - b * per_b4;
    const float4* p = (const float4*)(points + (size_t)b * 9 * ZYX);
    float4 v = p[f4];
    float vals[4] = {v.x, v.y, v.z, v.w};
    int f = f4 * 4;
#pragma unroll
    for (int k = 0; k < 4; ++k) {
        if (vals[k] > CLS_THR) {
            int pos = atomicAdd(&cnt[b], 1);
            if (pos < CAP) {
                csc[b * CAP + pos] = vals[k];
                cidx[b * CAP + pos] = f + k;
            }
        }
    }
}

// ---------------- kernel 2: rank, decode, NMS, emit -------------------------
__global__ __launch_bounds__(256) void nms_kernel(const float* __restrict__ points,
                                                  const int* __restrict__ cnt,
                                                  const float* __restrict__ csc,
                                                  const int* __restrict__ cidx,
                                                  float* __restrict__ out,
                                                  int B, int n_out) {
    __shared__ float s_rawsc[CAP];
    __shared__ int   s_rawidx[CAP];
    __shared__ float s_sc[MMAX];
    __shared__ int   s_idx[MMAX];
    __shared__ float s_x0[MMAX], s_y0[MMAX], s_x1[MMAX], s_y1[MMAX]; // xy boxes
    __shared__ float s_a0[MMAX], s_b0[MMAX], s_a1[MMAX], s_b1[MMAX]; // yz boxes
    __shared__ int   s_kept[KEPT_MAX];
    __shared__ int   s_nkept;

    int b = blockIdx.x;
    int tid = threadIdx.x;
    const float* pb = points + (size_t)b * 9 * ZYX;

    int V = cnt[b];
    if (V > CAP) V = CAP;
    for (int i = tid; i < V; i += 256) {
        s_rawsc[i] = csc[b * CAP + i];
        s_rawidx[i] = cidx[b * CAP + i];
    }
    __syncthreads();

    int M = V < MMAX ? V : MMAX;

    // exact ranking: descending score, ties -> ascending index (lax.top_k order)
    for (int i = tid; i < V; i += 256) {
        float si = s_rawsc[i];
        int ii = s_rawidx[i];
        int rank = 0;
        for (int j = 0; j < V; ++j) {
            float sj = s_rawsc[j];
            int ij = s_rawidx[j];
            rank += (sj > si) || (sj == si && ij < ii);
        }
        if (rank < MMAX) {
            s_sc[rank] = si;
            s_idx[rank] = ii;
        }
    }
    __syncthreads();

    // decode boxes for the M sorted candidates
    for (int m = tid; m < M; m += 256) {
        float cx, cy, cz, w, h, l, th;
        decode_one(pb, s_idx[m], cx, cy, cz, w, h, l, th);
        float xmn, ymn, xmx, ymx, zmn, zmx;
        corner_boxes(cx, cy, cz, w, h, l, th, xmn, ymn, xmx, ymx, zmn, zmx);
        s_x0[m] = xmn; s_y0[m] = ymn; s_x1[m] = xmx; s_y1[m] = ymx;
        s_a0[m] = ymn; s_b0[m] = zmn; s_a1[m] = ymx; s_b1[m] = zmx;
    }
    __syncthreads();

    // single-wave greedy NMS (xy and yz independently; keep = keep_xy | keep_yz)
    if (tid < 64) {
        int lane = tid;
        int n_kept = 0;
        unsigned sup_xy = 0u, sup_yz = 0u; // per-lane bitmask over slots (j = slot*64 + lane)
        int nslot = (M + 63) >> 6;
        int kept_cap = n_out < KEPT_MAX ? n_out : KEPT_MAX;
        for (int i = 0; i < M; ++i) {
            int owner = i & 63;
            int slot = i >> 6;
            unsigned mx = (unsigned)__shfl((int)sup_xy, owner, 64);
            unsigned my = (unsigned)__shfl((int)sup_yz, owner, 64);
            bool kx = !((mx >> slot) & 1u);
            bool ky = !((my >> slot) & 1u);
            if (!(kx || ky)) continue;       // uniform branch
            if (lane == 0 && n_kept < kept_cap) s_kept[n_kept] = i;
            n_kept++;
            if (n_kept >= kept_cap) break;   // later keeps can't affect output
            // box i (broadcast LDS reads)
            float ix0 = s_x0[i], iy0 = s_y0[i], ix1 = s_x1[i], iy1 = s_y1[i];
            float iaxy = fmaxf(ix1 - ix0, 0.0f) * fmaxf(iy1 - iy0, 0.0f);
            float ia0 = s_a0[i], ib0 = s_b0[i], ia1 = s_a1[i], ib1 = s_b1[i];
            float iayz = fmaxf(ia1 - ia0, 0.0f) * fmaxf(ib1 - ib0, 0.0f);
            for (int s = 0; s < nslot; ++s) {
                int j = (s << 6) | lane;
                if (j <= i || j >= M) continue;
                if (kx && !((sup_xy >> s) & 1u)) {
                    float x0 = s_x0[j], y0 = s_y0[j], x1 = s_x1[j], y1 = s_y1[j];
                    float area = fmaxf(x1 - x0, 0.0f) * fmaxf(y1 - y0, 0.0f);
                    float lt0 = fmaxf(ix0, x0), lt1 = fmaxf(iy0, y0);
                    float rb0 = fminf(ix1, x1), rb1 = fminf(iy1, y1);
                    float inter = fmaxf(rb0 - lt0, 0.0f) * fmaxf(rb1 - lt1, 0.0f);
                    float uni = iaxy + area - inter;
                    if (inter / fmaxf(uni, 1e-9f) > IOU_THR) sup_xy |= (1u << s);
                }
                if (ky && !((sup_yz >> s) & 1u)) {
                    float x0 = s_a0[j], y0 = s_b0[j], x1 = s_a1[j], y1 = s_b1[j];
                    float area = fmaxf(x1 - x0, 0.0f) * fmaxf(y1 - y0, 0.0f);
                    float lt0 = fmaxf(ia0, x0), lt1 = fmaxf(ib0, y0);
                    float rb0 = fminf(ia1, x1), rb1 = fminf(ib1, y1);
                    float inter = fmaxf(rb0 - lt0, 0.0f) * fmaxf(rb1 - lt1, 0.0f);
                    float uni = iayz + area - inter;
                    if (inter / fmaxf(uni, 1e-9f) > IOU_THR) sup_yz |= (1u << s);
                }
            }
        }
        if (lane == 0) {
            int nk = n_kept < kept_cap ? n_kept : kept_cap;
            s_nkept = nk;
        }
    }
    __syncthreads();

    // emit: boxes (B, n_out, 9) then scores (B, n_out); zero-pad beyond n_kept
    int nk = s_nkept;
    float* boxes_out = out;
    float* scores_out = out + (size_t)B * n_out * 9;
    for (int p = tid; p < n_out; p += 256) {
        float o[9] = {0, 0, 0, 0, 0, 0, 0, 0, 0};
        float sc = 0.0f;
        if (p < nk) {
            int m = s_kept[p];
            float cx, cy, cz, w, h, l, th;
            decode_one(pb, s_idx[m], cx, cy, cz, w, h, l, th);
            o[0] = cx; o[1] = cy; o[2] = cz;
            o[3] = w;  o[4] = h;  o[5] = l;
            o[6] = 0.0f; o[7] = th; o[8] = 0.0f;
            sc = s_sc[m];
        }
        float* bo = boxes_out + ((size_t)b * n_out + p) * 9;
#pragma unroll
        for (int k = 0; k < 9; ++k) bo[k] = o[k];
        scores_out[(size_t)b * n_out + p] = sc;
    }
}

extern "C" void kernel_launch(void* const* d_in, const int* in_sizes, int n_in,
                              void* d_out, int out_size, void* d_ws, size_t ws_size,
                              hipStream_t stream) {
    const float* points = (const float*)d_in[0];
    int B = in_sizes[0] / (9 * ZYX);            // 4
    int n_out = out_size / (B * 10);            // 50  (9 box vals + 1 score per slot)

    char* ws = (char*)d_ws;
    int* cnt = (int*)ws;                                        // B counters
    float* csc = (float*)(ws + 256);                            // B*CAP scores
    int* cidx = (int*)(ws + 256 + (size_t)B * CAP * sizeof(float)); // B*CAP indices

    hipMemsetAsync(cnt, 0, 256, stream);

    int total4 = B * (ZYX / 4);
    collect_kernel<<<(total4 + 255) / 256, 256, 0, stream>>>(points, B, cnt, csc, cidx);
    nms_kernel<<<B, 256, 0, stream>>>(points, cnt, csc, cidx, (float*)d_out, B, n_out);
}